// Round 3
// baseline (14330.183 us; speedup 1.0000x reference)
//
#include <hip/hip_runtime.h>
#include <hip/hip_bf16.h>

// ---- problem constants ----
constexpr int kB   = 32;
constexpr int kL   = 12;
constexpr int kN   = 325;
constexpr int kNP  = 328;          // padded node count
constexpr int kPc  = kB * kNP;     // 10496 column stride, channel-major
constexpr int kHID = 64;
constexpr int kDIN = 198;          // 3 * 66
constexpr int kND  = 40;
constexpr float cAW = 0.05f, cBW = 0.95f, cGW = 0.95f, cTA = 3.0f;

__device__ __forceinline__ float sigm_f(float x) { return 1.f / (1.f + __expf(-x)); }
__device__ __forceinline__ float tanh_f(float x) { return 1.f - 2.f / (1.f + __expf(2.f * x)); }

// ---------------------------------------------------------------------------
// init: xH rows 0..1 = hist[t=0], rows 2..65 = 0 (H0); emb transposes
__global__ void k_init(const float* __restrict__ hist,
                       const float* __restrict__ emb1, const float* __restrict__ emb2,
                       float* __restrict__ xH, float* __restrict__ e1T, float* __restrict__ e2T) {
    int tid = blockIdx.x * 256 + threadIdx.x;
    if (tid < 66 * kPc) {
        int c = tid / kPc, p = tid - c * kPc;
        int b = p / kNP, n = p - b * kNP;
        if (n >= kN) return;
        float v = 0.f;
        if (c < 2) v = hist[((b * kL + 0) * kN + n) * 2 + c];
        xH[c * kPc + p] = v;
        return;
    }
    tid -= 66 * kPc;
    if (tid < 40 * kN) { int d = tid / kN, n = tid - d * kN; e1T[tid] = emb1[n * kND + d]; return; }
    tid -= 40 * kN;
    if (tid < 40 * kN) { int d = tid / kN, n = tid - d * kN; e2T[tid] = emb2[n * kND + d]; }
}

// ---------------------------------------------------------------------------
// diffusion hop with LDS-staged M tile shared across channels.
// out[c,b,w] = gamma * sum_v M[v,w] * h[c,b,v] + AW * x[c,b,w]
// grid (6 wblk, 64 = b + 32*chain, 2 cgroup), block 256 (4 waves)
__global__ __launch_bounds__(256) void k_hop(
        const float* __restrict__ Ma, const float* __restrict__ Mb, int mstride,
        const float* __restrict__ hA, const float* __restrict__ hB,
        const float* __restrict__ xS,
        float* __restrict__ oA, float* __restrict__ oB, float gamma) {
    __shared__ float mt[2][16][64];
    const int lane = threadIdx.x & 63;
    const int wv = __builtin_amdgcn_readfirstlane(threadIdx.x >> 6);
    const int w0 = blockIdx.x * 64;
    const int w = w0 + lane;
    const int yb = blockIdx.y;
    const int sel = yb >> 5, b = yb & 31;
    const int cg = blockIdx.z;
    const float* M = (sel ? Mb : Ma) + (size_t)b * mstride;
    const float* h = (sel ? hB : hA) + b * kNP;
    const float* x = xS + b * kNP;
    float* o = (sel ? oB : oA) + b * kNP;
    const int cbase = cg * 33;
    const int cstart = cbase + (wv ? 9 + (wv - 1) * 8 : 0);
    const int ccnt = wv ? 8 : 9;

    float acc[9];
#pragma unroll
    for (int i = 0; i < 9; ++i) acc[i] = 0.f;

    const int nck = (kN + 15) / 16;   // 21
    // stage chunk 0
    {
#pragma unroll
        for (int rr = 0; rr < 4; ++rr) {
            int r = wv * 4 + rr;
            int v = r;
            mt[0][r][lane] = (v < kN && w < kN) ? M[(size_t)v * kN + w] : 0.f;
        }
    }
    for (int ck = 0; ck < nck; ++ck) {
        __syncthreads();
        if (ck + 1 < nck) {
            int v0n = (ck + 1) * 16;
#pragma unroll
            for (int rr = 0; rr < 4; ++rr) {
                int r = wv * 4 + rr;
                int v = v0n + r;
                mt[(ck + 1) & 1][r][lane] = (v < kN && w < kN) ? M[(size_t)v * kN + w] : 0.f;
            }
        }
        const int bi = ck & 1;
        const int v0 = ck * 16;
        float mr[16];
#pragma unroll
        for (int r = 0; r < 16; ++r) mr[r] = mt[bi][r][lane];
#pragma unroll
        for (int i = 0; i < 9; ++i) {
            if (i < ccnt) {
                const float* hr = h + (size_t)(cstart + i) * kPc + v0;
                float4 A0 = *(const float4*)(hr);
                float4 A1 = *(const float4*)(hr + 4);
                float4 A2 = *(const float4*)(hr + 8);
                float4 A3 = *(const float4*)(hr + 12);
                float s = acc[i];
                s = fmaf(mr[0],  A0.x, s); s = fmaf(mr[1],  A0.y, s);
                s = fmaf(mr[2],  A0.z, s); s = fmaf(mr[3],  A0.w, s);
                s = fmaf(mr[4],  A1.x, s); s = fmaf(mr[5],  A1.y, s);
                s = fmaf(mr[6],  A1.z, s); s = fmaf(mr[7],  A1.w, s);
                s = fmaf(mr[8],  A2.x, s); s = fmaf(mr[9],  A2.y, s);
                s = fmaf(mr[10], A2.z, s); s = fmaf(mr[11], A2.w, s);
                s = fmaf(mr[12], A3.x, s); s = fmaf(mr[13], A3.y, s);
                s = fmaf(mr[14], A3.z, s); s = fmaf(mr[15], A3.w, s);
                acc[i] = s;
            }
        }
    }
    if (w < kN) {
#pragma unroll
        for (int i = 0; i < 9; ++i)
            if (i < ccnt) {
                size_t idx = (size_t)(cstart + i) * kPc + w;
                o[idx] = gamma * acc[i] + cAW * x[idx];
            }
    }
}

// ---------------------------------------------------------------------------
// fused hyper MLP: fc1(198->16,sig) with K-split-3 + fc2(16->2,sig) + fc3(2->40)
// + combine + nv = tanh(TA*emb*f).  grid (164), block 768 (12 waves: s*4+m)
__global__ __launch_bounds__(768) void k_mlp(
        const float* __restrict__ xH,
        const float* __restrict__ h01, const float* __restrict__ h11,
        const float* __restrict__ h02, const float* __restrict__ h12,
        const float* __restrict__ w1, const float* __restrict__ b1,
        const float* __restrict__ w2, const float* __restrict__ b2,
        const float* __restrict__ w3, const float* __restrict__ b3,
        const float* __restrict__ e1T, const float* __restrict__ e2T,
        float* __restrict__ nv1, float* __restrict__ nv2, int hy0) {
    __shared__ float part[12][16][64];
    __shared__ float s2s[4][2][64];
    const int lane = threadIdx.x & 63;
    const int wv = __builtin_amdgcn_readfirstlane(threadIdx.x >> 6);
    const int p = blockIdx.x * 64 + lane;
    const int m = wv & 3, s = wv >> 2;
    const int ig = hy0 + m;
    const float* src = (s == 0) ? xH : (s == 1) ? ((m & 1) ? h11 : h01)
                                               : ((m & 1) ? h12 : h02);
    const float* wp = w1 + (size_t)ig * (kDIN * 16);
    float acc[16];
#pragma unroll
    for (int o = 0; o < 16; ++o) acc[o] = 0.f;
#pragma unroll 2
    for (int kl = 0; kl < 66; ++kl) {
        int kk = s * 66 + kl;
        float u = src[(size_t)kl * kPc + p];
        float4 wa = *(const float4*)(wp + kk * 16);
        float4 wb = *(const float4*)(wp + kk * 16 + 4);
        float4 wc = *(const float4*)(wp + kk * 16 + 8);
        float4 wd = *(const float4*)(wp + kk * 16 + 12);
        acc[0]  = fmaf(u, wa.x, acc[0]);  acc[1]  = fmaf(u, wa.y, acc[1]);
        acc[2]  = fmaf(u, wa.z, acc[2]);  acc[3]  = fmaf(u, wa.w, acc[3]);
        acc[4]  = fmaf(u, wb.x, acc[4]);  acc[5]  = fmaf(u, wb.y, acc[5]);
        acc[6]  = fmaf(u, wb.z, acc[6]);  acc[7]  = fmaf(u, wb.w, acc[7]);
        acc[8]  = fmaf(u, wc.x, acc[8]);  acc[9]  = fmaf(u, wc.y, acc[9]);
        acc[10] = fmaf(u, wc.z, acc[10]); acc[11] = fmaf(u, wc.w, acc[11]);
        acc[12] = fmaf(u, wd.x, acc[12]); acc[13] = fmaf(u, wd.y, acc[13]);
        acc[14] = fmaf(u, wd.z, acc[14]); acc[15] = fmaf(u, wd.w, acc[15]);
    }
#pragma unroll
    for (int o = 0; o < 16; ++o) part[wv][o][lane] = acc[o];
    __syncthreads();
    if (wv < 4) {
        int mm = wv, igm = hy0 + mm;
        float sv[16];
#pragma unroll
        for (int o = 0; o < 16; ++o)
            sv[o] = sigm_f(b1[igm * 16 + o] + part[mm][o][lane] + part[4 + mm][o][lane] + part[8 + mm][o][lane]);
#pragma unroll
        for (int j = 0; j < 2; ++j) {
            float t = b2[igm * 2 + j];
#pragma unroll
            for (int o = 0; o < 16; ++o) t = fmaf(sv[o], w2[igm * 32 + o * 2 + j], t);
            s2s[mm][j][lane] = sigm_f(t);
        }
    }
    __syncthreads();
    int b = p / kNP, n = p - b * kNP;
    int nc = (n < kN) ? n : (kN - 1);
    bool ok = (n < kN);
    if (wv < 2) {
        int i0 = hy0 + wv * 2;
        float sa0 = s2s[wv * 2 + 0][0][lane], sa1 = s2s[wv * 2 + 0][1][lane];
        float sb0 = s2s[wv * 2 + 1][0][lane], sb1 = s2s[wv * 2 + 1][1][lane];
        const float* eT = wv ? e2T : e1T;
        float* nv = wv ? nv2 : nv1;
#pragma unroll 4
        for (int d = 0; d < kND; ++d) {
            float f = b3[(i0 + 0) * kND + d] + b3[(i0 + 1) * kND + d]
                    + sa0 * w3[(i0 + 0) * 80 + d] + sa1 * w3[(i0 + 0) * 80 + 40 + d]
                    + sb0 * w3[(i0 + 1) * 80 + d] + sb1 * w3[(i0 + 1) * 80 + 40 + d];
            float r = tanh_f(cTA * eT[d * kN + nc] * f);
            if (ok) nv[(size_t)d * kPc + p] = r;
        }
    }
}

// ---------------------------------------------------------------------------
// fused a-GEMM + antisymmetrize: adjv[i][j] = relu(tanh(TA*(a_ij - a_ji)))
__global__ __launch_bounds__(64) void k_adj(const float* __restrict__ nv1, const float* __restrict__ nv2,
                                            float* __restrict__ adjv) {
    int j = blockIdx.x * 64 + threadIdx.x;
    if (j >= kN) return;
    int i0 = blockIdx.y * 16;
    int b = blockIdx.z;
    const float* p1 = nv1 + b * kNP;
    const float* p2 = nv2 + b * kNP;
    float aij[16], aji[16];
#pragma unroll
    for (int q = 0; q < 16; ++q) { aij[q] = 0.f; aji[q] = 0.f; }
#pragma unroll 2
    for (int d = 0; d < kND; ++d) {
        const float* r1 = p1 + (size_t)d * kPc;
        const float* r2 = p2 + (size_t)d * kPc;
        float x1j = r1[j];
        float x2j = r2[j];
        float4 v1a = *(const float4*)(r1 + i0);
        float4 v1b = *(const float4*)(r1 + i0 + 4);
        float4 v1c = *(const float4*)(r1 + i0 + 8);
        float4 v1d = *(const float4*)(r1 + i0 + 12);
        float4 v2a = *(const float4*)(r2 + i0);
        float4 v2b = *(const float4*)(r2 + i0 + 4);
        float4 v2c = *(const float4*)(r2 + i0 + 8);
        float4 v2d = *(const float4*)(r2 + i0 + 12);
        float w1v[16] = {v1a.x,v1a.y,v1a.z,v1a.w, v1b.x,v1b.y,v1b.z,v1b.w,
                         v1c.x,v1c.y,v1c.z,v1c.w, v1d.x,v1d.y,v1d.z,v1d.w};
        float w2v[16] = {v2a.x,v2a.y,v2a.z,v2a.w, v2b.x,v2b.y,v2b.z,v2b.w,
                         v2c.x,v2c.y,v2c.z,v2c.w, v2d.x,v2d.y,v2d.z,v2d.w};
#pragma unroll
        for (int q = 0; q < 16; ++q) {
            aij[q] = fmaf(w1v[q], x2j, aij[q]);
            aji[q] = fmaf(x1j, w2v[q], aji[q]);
        }
    }
    size_t base = (size_t)b * kN * kN;
#pragma unroll
    for (int q = 0; q < 16; ++q) {
        int i = i0 + q;
        if (i < kN) {
            float tv = tanh_f(cTA * (aij[q] - aji[q]));
            adjv[base + (size_t)i * kN + j] = fmaxf(tv, 0.f);
        }
    }
}

// merged row/col sums: z=0 colsum (irs1), z=1 rowsum (irs0)
__global__ __launch_bounds__(256) void k_sums(const float* __restrict__ adjv,
                                              float* __restrict__ irs0, float* __restrict__ irs1) {
    int b = blockIdx.y;
    const float* base = adjv + (size_t)b * kN * kN;
    int lane = threadIdx.x & 63, wv = threadIdx.x >> 6;
    if (blockIdx.z == 0) {
        if (blockIdx.x >= 6) return;
        __shared__ float red[4][64];
        int i = blockIdx.x * 64 + lane;
        float cs = 0.f;
        if (i < kN)
            for (int j = wv; j < kN; j += 4) cs += base[(size_t)j * kN + i];
        red[wv][lane] = cs;
        __syncthreads();
        if (wv == 0 && i < kN)
            irs1[b * kN + i] = 1.f / (1.f + red[0][lane] + red[1][lane] + red[2][lane] + red[3][lane]);
    } else {
        int i = blockIdx.x * 4 + wv;
        if (i >= kN) return;
        const float* row = base + (size_t)i * kN;
        float s = 0.f;
        for (int j = lane; j < kN; j += 64) s += row[j];
#pragma unroll
        for (int off = 32; off; off >>= 1) s += __shfl_down(s, off);
        if (lane == 0) irs0[b * kN + i] = 1.f / (1.f + s);
    }
}

// E0[v][w] = BW*(adjv[v][w]+I)*irs0[v] + GW*adj0[v][w]
// E1[v][w] = BW*(adjv[w][v]+I)*irs1[v] + GW*adj1[v][w]
__global__ __launch_bounds__(256) void k_buildE(const float* __restrict__ adjv,
                                                const float* __restrict__ adj0, const float* __restrict__ adj1,
                                                const float* __restrict__ irs0, const float* __restrict__ irs1,
                                                float* __restrict__ E0, float* __restrict__ E1) {
    __shared__ float tile[64][65];
    int lane = threadIdx.x & 63, wv = threadIdx.x >> 6;
    int w0 = blockIdx.x * 64, v0 = blockIdx.y * 64, b = blockIdx.z;
    const float* av = adjv + (size_t)b * kN * kN;
#pragma unroll 4
    for (int rr = 0; rr < 16; ++rr) {
        int r = wv * 16 + rr;
        int v = v0 + r, w = w0 + lane;
        tile[r][lane] = (v < kN && w < kN) ? av[(size_t)v * kN + w] : 0.f;
    }
    __syncthreads();
    size_t eb = (size_t)b * kN * kN;
#pragma unroll 2
    for (int rr = 0; rr < 16; ++rr) {
        int r = wv * 16 + rr;
        {
            int v = v0 + r, w = w0 + lane;
            if (v < kN && w < kN) {
                float iv = irs0[b * kN + v];
                float e = cBW * tile[r][lane] * iv + cGW * adj0[v * kN + w];
                if (v == w) e += cBW * iv;
                E0[eb + (size_t)v * kN + w] = e;
            }
        }
        {
            int v = w0 + r, w = v0 + lane;
            if (v < kN && w < kN) {
                float iv = irs1[b * kN + v];
                float e = cBW * tile[lane][r] * iv + cGW * adj1[v * kN + w];
                if (v == w) e += cBW * iv;
                E1[eb + (size_t)v * kN + w] = e;
            }
        }
    }
}

// ---------------------------------------------------------------------------
// z,r gates + temp=[x, r*H] into tmp. grid (164,4), block 256; LDS-staged u.
__global__ __launch_bounds__(256) void k_gates(
        const float* __restrict__ xH,
        const float* __restrict__ a1, const float* __restrict__ a2,   // chain0 hops
        const float* __restrict__ c1, const float* __restrict__ c2,   // chain1 hops
        const float* __restrict__ rnw, const float* __restrict__ rnb, int rb,
        float* __restrict__ z, float* __restrict__ tmp) {
    __shared__ float ut[2][2][8][64];
    const int lane = threadIdx.x & 63;
    const int wv = __builtin_amdgcn_readfirstlane(threadIdx.x >> 6);
    const int p = blockIdx.x * 64 + lane;
    const int h0 = blockIdx.y * 16 + wv * 4;
    const float* pz0 = rnw + (size_t)(rb + 0) * (kDIN * kHID) + h0;
    const float* pz1 = rnw + (size_t)(rb + 1) * (kDIN * kHID) + h0;
    const float* pr0 = rnw + (size_t)(rb + 2) * (kDIN * kHID) + h0;
    const float* pr1 = rnw + (size_t)(rb + 3) * (kDIN * kHID) + h0;

    auto stage = [&](int bi, int k0) {
#pragma unroll
        for (int rr = 0; rr < 4; ++rr) {
            int r = wv * 4 + rr;
            int srci = r >> 3, k = r & 7;
            int kk = k0 + k;
            float v = 0.f;
            if (kk < kDIN) {
                int seg = kk < 66 ? 0 : (kk < 132 ? 1 : 2);
                int kl = kk - seg * 66;
                const float* sp = srci ? (seg == 0 ? xH : seg == 1 ? c1 : c2)
                                       : (seg == 0 ? xH : seg == 1 ? a1 : a2);
                v = sp[(size_t)kl * kPc + p];
            }
            ut[bi][srci][k][lane] = v;
        }
    };

    float az[4] = {0.f, 0.f, 0.f, 0.f}, ar[4] = {0.f, 0.f, 0.f, 0.f};
    const int nck = 25;
    stage(0, 0);
    for (int ck = 0; ck < nck; ++ck) {
        __syncthreads();
        if (ck + 1 < nck) stage((ck + 1) & 1, (ck + 1) * 8);
        const int bi = ck & 1;
#pragma unroll
        for (int k = 0; k < 8; ++k) {
            int kk = ck * 8 + k;
            int kks = (kk < kDIN) ? kk : (kDIN - 1);
            float u0 = ut[bi][0][k][lane], u1 = ut[bi][1][k][lane];
            float4 wz0 = *(const float4*)(pz0 + (size_t)kks * kHID);
            float4 wz1 = *(const float4*)(pz1 + (size_t)kks * kHID);
            float4 wr0 = *(const float4*)(pr0 + (size_t)kks * kHID);
            float4 wr1 = *(const float4*)(pr1 + (size_t)kks * kHID);
            az[0] = fmaf(u0, wz0.x, az[0]); az[1] = fmaf(u0, wz0.y, az[1]);
            az[2] = fmaf(u0, wz0.z, az[2]); az[3] = fmaf(u0, wz0.w, az[3]);
            az[0] = fmaf(u1, wz1.x, az[0]); az[1] = fmaf(u1, wz1.y, az[1]);
            az[2] = fmaf(u1, wz1.z, az[2]); az[3] = fmaf(u1, wz1.w, az[3]);
            ar[0] = fmaf(u0, wr0.x, ar[0]); ar[1] = fmaf(u0, wr0.y, ar[1]);
            ar[2] = fmaf(u0, wr0.z, ar[2]); ar[3] = fmaf(u0, wr0.w, ar[3]);
            ar[0] = fmaf(u1, wr1.x, ar[0]); ar[1] = fmaf(u1, wr1.y, ar[1]);
            ar[2] = fmaf(u1, wr1.z, ar[2]); ar[3] = fmaf(u1, wr1.w, ar[3]);
        }
    }
    int b = p / kNP, n = p - b * kNP;
    bool ok = (n < kN);
#pragma unroll
    for (int i = 0; i < 4; ++i) {
        float zz = sigm_f(az[i] + rnb[(rb + 0) * kHID + h0 + i] + rnb[(rb + 1) * kHID + h0 + i]);
        float rr = sigm_f(ar[i] + rnb[(rb + 2) * kHID + h0 + i] + rnb[(rb + 3) * kHID + h0 + i]);
        float tv = rr * xH[(size_t)(2 + h0 + i) * kPc + p];
        if (ok) {
            z[(size_t)(h0 + i) * kPc + p] = zz;
            tmp[(size_t)(2 + h0 + i) * kPc + p] = tv;
        }
    }
    if (blockIdx.y == 0 && wv == 0 && ok) {
        tmp[p] = xH[p];
        tmp[kPc + p] = xH[kPc + p];
    }
}

// ---------------------------------------------------------------------------
// Cn + GRU update (in place on xH rows 2..65) + next-step x rows.
// nextmode: 0 = enc next (hist t+1), 1 = first dec (0, fut tod 0), 2 = dec (skip)
__global__ __launch_bounds__(256) void k_final(
        const float* __restrict__ tmp,
        const float* __restrict__ a1, const float* __restrict__ a2,
        const float* __restrict__ c1, const float* __restrict__ c2,
        const float* __restrict__ rnw, const float* __restrict__ rnb, int rb,
        const float* __restrict__ z, float* __restrict__ xH,
        const float* __restrict__ hist, const float* __restrict__ fut,
        int t, int nextmode) {
    __shared__ float ut[2][2][8][64];
    const int lane = threadIdx.x & 63;
    const int wv = __builtin_amdgcn_readfirstlane(threadIdx.x >> 6);
    const int p = blockIdx.x * 64 + lane;
    const int h0 = blockIdx.y * 16 + wv * 4;
    const float* pc0 = rnw + (size_t)(rb + 4) * (kDIN * kHID) + h0;
    const float* pc1 = rnw + (size_t)(rb + 5) * (kDIN * kHID) + h0;

    auto stage = [&](int bi, int k0) {
#pragma unroll
        for (int rr = 0; rr < 4; ++rr) {
            int r = wv * 4 + rr;
            int srci = r >> 3, k = r & 7;
            int kk = k0 + k;
            float v = 0.f;
            if (kk < kDIN) {
                int seg = kk < 66 ? 0 : (kk < 132 ? 1 : 2);
                int kl = kk - seg * 66;
                const float* sp = srci ? (seg == 0 ? tmp : seg == 1 ? c1 : c2)
                                       : (seg == 0 ? tmp : seg == 1 ? a1 : a2);
                v = sp[(size_t)kl * kPc + p];
            }
            ut[bi][srci][k][lane] = v;
        }
    };

    float ac[4] = {0.f, 0.f, 0.f, 0.f};
    const int nck = 25;
    stage(0, 0);
    for (int ck = 0; ck < nck; ++ck) {
        __syncthreads();
        if (ck + 1 < nck) stage((ck + 1) & 1, (ck + 1) * 8);
        const int bi = ck & 1;
#pragma unroll
        for (int k = 0; k < 8; ++k) {
            int kk = ck * 8 + k;
            int kks = (kk < kDIN) ? kk : (kDIN - 1);
            float u0 = ut[bi][0][k][lane], u1 = ut[bi][1][k][lane];
            float4 w0 = *(const float4*)(pc0 + (size_t)kks * kHID);
            float4 w1 = *(const float4*)(pc1 + (size_t)kks * kHID);
            ac[0] = fmaf(u0, w0.x, ac[0]); ac[1] = fmaf(u0, w0.y, ac[1]);
            ac[2] = fmaf(u0, w0.z, ac[2]); ac[3] = fmaf(u0, w0.w, ac[3]);
            ac[0] = fmaf(u1, w1.x, ac[0]); ac[1] = fmaf(u1, w1.y, ac[1]);
            ac[2] = fmaf(u1, w1.z, ac[2]); ac[3] = fmaf(u1, w1.w, ac[3]);
        }
    }
    int b = p / kNP, n = p - b * kNP;
    bool ok = (n < kN);
#pragma unroll
    for (int i = 0; i < 4; ++i) {
        float cn = tanh_f(ac[i] + rnb[(rb + 4) * kHID + h0 + i] + rnb[(rb + 5) * kHID + h0 + i]);
        float zz = z[(size_t)(h0 + i) * kPc + p];
        size_t hidx = (size_t)(2 + h0 + i) * kPc + p;
        float hv = xH[hidx];
        if (ok) xH[hidx] = zz * hv + (1.f - zz) * cn;
    }
    if (blockIdx.y == 0 && wv == 0 && ok && nextmode != 2) {
        float r0, r1;
        if (nextmode == 0) {
            r0 = hist[((b * kL + (t + 1)) * kN + n) * 2 + 0];
            r1 = hist[((b * kL + (t + 1)) * kN + n) * 2 + 1];
        } else {
            r0 = 0.f;
            r1 = fut[((b * kL + 0) * kN + n) * 2 + 1];
        }
        xH[p] = r0;
        xH[kPc + p] = r1;
    }
}

// decoder readout: out = H @ fc_w + fc_b ; also write next dec x rows
__global__ __launch_bounds__(64) void k_out(const float* __restrict__ xH,
                                            const float* __restrict__ fw, const float* __restrict__ fb,
                                            float* __restrict__ out, const float* __restrict__ fut,
                                            float* __restrict__ xHw, int t) {
    int p = blockIdx.x * 64 + threadIdx.x;
    int b = p / kNP, n = p - b * kNP;
    if (n >= kN) return;
    float acc = fb[0];
#pragma unroll
    for (int h = 0; h < kHID; ++h) acc = fmaf(xH[(size_t)(2 + h) * kPc + p], fw[h], acc);
    out[(b * 12 + t) * kN + n] = acc;
    if (t + 1 < 12) {
        xHw[p] = acc;
        xHw[kPc + p] = fut[((b * kL + (t + 1)) * kN + n) * 2 + 1];
    }
}

// ---------------------------------------------------------------------------
extern "C" void kernel_launch(void* const* d_in, const int* in_sizes, int n_in,
                              void* d_out, int out_size, void* d_ws, size_t ws_size,
                              hipStream_t stream) {
    const float* hist = (const float*)d_in[0];
    const float* fut  = (const float*)d_in[1];
    const float* adj0 = (const float*)d_in[2];
    const float* adj1 = (const float*)d_in[3];
    const float* emb1 = (const float*)d_in[4];
    const float* emb2 = (const float*)d_in[5];
    const float* hw1  = (const float*)d_in[6];
    const float* hb1  = (const float*)d_in[7];
    const float* hw2  = (const float*)d_in[8];
    const float* hb2  = (const float*)d_in[9];
    const float* hw3  = (const float*)d_in[10];
    const float* hb3  = (const float*)d_in[11];
    const float* rnw  = (const float*)d_in[12];
    const float* rnb  = (const float*)d_in[13];
    const float* fcw  = (const float*)d_in[14];
    const float* fcb  = (const float*)d_in[15];
    float* out = (float*)d_out;
    float* ws  = (float*)d_ws;

    const size_t SEG = (size_t)66 * kPc;
    size_t off = 0;
    float* xH   = ws + off; off += SEG;
    float* hy0h1= ws + off; off += SEG;
    float* hy1h1= ws + off; off += SEG;
    float* hy0h2= ws + off; off += SEG;
    float* hy1h2= ws + off; off += SEG;
    float* z0h1 = ws + off; off += SEG;
    float* z1h1 = ws + off; off += SEG;
    float* z0h2 = ws + off; off += SEG;
    float* z1h2 = ws + off; off += SEG;
    float* tmp  = ws + off; off += SEG;
    float* c0h1 = ws + off; off += SEG;
    float* c1h1 = ws + off; off += SEG;
    float* c0h2 = ws + off; off += SEG;
    float* c1h2 = ws + off; off += SEG;
    float* nv1  = ws + off; off += (size_t)kND * kPc;
    float* nv2  = ws + off; off += (size_t)kND * kPc;
    float* zbuf = ws + off; off += (size_t)64 * kPc;
    float* e1T  = ws + off; off += kND * kN;
    float* e2T  = ws + off; off += kND * kN;
    float* irs0 = ws + off; off += kB * kN;
    float* irs1 = ws + off; off += kB * kN;
    float* adjv = ws + off; off += (size_t)kB * kN * kN;
    float* E0   = ws + off; off += (size_t)kB * kN * kN;
    float* E1   = ws + off; off += (size_t)kB * kN * kN;

    const int NN2 = kN * kN;

    {
        int tot = 66 * kPc + 2 * kND * kN;
        k_init<<<dim3((tot + 255) / 256), dim3(256), 0, stream>>>(hist, emb1, emb2, xH, e1T, e2T);
    }

    for (int step = 0; step < 24; ++step) {
        int dec = step >= 12;
        int t = dec ? step - 12 : step;
        int hy0 = dec ? 4 : 0;
        int rb = dec ? 6 : 0;
        int nextmode = dec ? 2 : (step == 11 ? 1 : 0);

        // hyper diffusion
        k_hop<<<dim3(6, 64, 2), dim3(256), 0, stream>>>(
            adj0, adj1, 0, xH, xH, xH, hy0h1, hy1h1, cGW);
        k_hop<<<dim3(6, 64, 2), dim3(256), 0, stream>>>(
            adj0, adj1, 0, hy0h1, hy1h1, xH, hy0h2, hy1h2, cGW);

        k_mlp<<<dim3(kPc / 64), dim3(768), 0, stream>>>(
            xH, hy0h1, hy1h1, hy0h2, hy1h2, hw1, hb1, hw2, hb2, hw3, hb3,
            e1T, e2T, nv1, nv2, hy0);

        k_adj<<<dim3(6, 21, kB), dim3(64), 0, stream>>>(nv1, nv2, adjv);
        k_sums<<<dim3(82, kB, 2), dim3(256), 0, stream>>>(adjv, irs0, irs1);
        k_buildE<<<dim3(6, 6, kB), dim3(256), 0, stream>>>(adjv, adj0, adj1, irs0, irs1, E0, E1);

        // z/r diffusion
        k_hop<<<dim3(6, 64, 2), dim3(256), 0, stream>>>(
            E0, E1, NN2, xH, xH, xH, z0h1, z1h1, 1.f);
        k_hop<<<dim3(6, 64, 2), dim3(256), 0, stream>>>(
            E0, E1, NN2, z0h1, z1h1, xH, z0h2, z1h2, 1.f);

        k_gates<<<dim3(kPc / 64, 4), dim3(256), 0, stream>>>(
            xH, z0h1, z0h2, z1h1, z1h2, rnw, rnb, rb, zbuf, tmp);

        // candidate diffusion
        k_hop<<<dim3(6, 64, 2), dim3(256), 0, stream>>>(
            E0, E1, NN2, tmp, tmp, tmp, c0h1, c1h1, 1.f);
        k_hop<<<dim3(6, 64, 2), dim3(256), 0, stream>>>(
            E0, E1, NN2, c0h1, c1h1, tmp, c0h2, c1h2, 1.f);

        k_final<<<dim3(kPc / 64, 4), dim3(256), 0, stream>>>(
            tmp, c0h1, c0h2, c1h1, c1h2, rnw, rnb, rb, zbuf, xH, hist, fut, t, nextmode);

        if (dec)
            k_out<<<dim3(kPc / 64), dim3(64), 0, stream>>>(xH, fcw, fcb, out, fut, xH, t);
    }
    (void)in_sizes; (void)n_in; (void)out_size; (void)ws_size;
}

// Round 4
// 13270.375 us; speedup vs baseline: 1.0799x; 1.0799x over previous
//
#include <hip/hip_runtime.h>
#include <hip/hip_bf16.h>

// ---- problem constants ----
constexpr int kB   = 32;
constexpr int kL   = 12;
constexpr int kN   = 325;
constexpr int kNP  = 328;          // padded node count
constexpr int kPc  = kB * kNP;     // 10496 column stride, channel-major
constexpr int kHID = 64;
constexpr int kDIN = 198;          // 3 * 66
constexpr int kND  = 40;
constexpr float cAW = 0.05f, cBW = 0.95f, cGW = 0.95f, cTA = 3.0f;

__device__ __forceinline__ float sigm_f(float x) { return 1.f / (1.f + __expf(-x)); }
__device__ __forceinline__ float tanh_f(float x) { return 1.f - 2.f / (1.f + __expf(2.f * x)); }

// ---------------------------------------------------------------------------
// init: xH rows 0..1 = hist[t=0], rows 2..65 = 0 (H0); emb transposes
__global__ void k_init(const float* __restrict__ hist,
                       const float* __restrict__ emb1, const float* __restrict__ emb2,
                       float* __restrict__ xH, float* __restrict__ e1T, float* __restrict__ e2T) {
    int tid = blockIdx.x * 256 + threadIdx.x;
    if (tid < 66 * kPc) {
        int c = tid / kPc, p = tid - c * kPc;
        int b = p / kNP, n = p - b * kNP;
        if (n >= kN) return;
        float v = 0.f;
        if (c < 2) v = hist[((b * kL + 0) * kN + n) * 2 + c];
        xH[c * kPc + p] = v;
        return;
    }
    tid -= 66 * kPc;
    if (tid < 40 * kN) { int d = tid / kN, n = tid - d * kN; e1T[tid] = emb1[n * kND + d]; return; }
    tid -= 40 * kN;
    if (tid < 40 * kN) { int d = tid / kN, n = tid - d * kN; e2T[tid] = emb2[n * kND + d]; }
}

// ---------------------------------------------------------------------------
// diffusion hop, barrier-free K-split across 3 waves of a 192-thread block.
// out[c,b,w] = gamma * sum_v M[v,w] * h[c,b,v] + AW * x[c,b,w]
// grid (6 wblk, 3 cblk, 64 = chain*32 + b), block 192.
// Wave wv covers K-range [vlo,vhi); waves 1,2 deposit partials in LDS,
// single barrier, wave 0 combines and stores. 22 channels per wave.
__global__ __launch_bounds__(192) void k_hop(
        const float* __restrict__ Ma, const float* __restrict__ Mb, int mstride,
        const float* __restrict__ hA, const float* __restrict__ hB,
        const float* __restrict__ xS,
        float* __restrict__ oA, float* __restrict__ oB, float gamma) {
    __shared__ float partial[2][22][64];
    const int lane = threadIdx.x & 63;
    const int wv = __builtin_amdgcn_readfirstlane(threadIdx.x >> 6);
    const int w = blockIdx.x * 64 + lane;
    const int wcl = (w < kN) ? w : (kN - 1);
    const int c0 = blockIdx.y * 22;
    const int zb = blockIdx.z;
    const int sel = zb >> 5, b = zb & 31;
    const float* M = (sel ? Mb : Ma) + (size_t)b * mstride;
    const float* h = (sel ? hB : hA) + b * kNP;
    const float* x = xS + b * kNP;
    float* o = (sel ? oB : oA) + b * kNP;
    const int vlo = (wv == 0) ? 0 : (wv == 1) ? 108 : 216;
    const int vhi = (wv == 0) ? 108 : (wv == 1) ? 216 : kN;
    const float* Mp = M + wcl;

    float acc[22];
#pragma unroll
    for (int i = 0; i < 22; ++i) acc[i] = 0.f;

    int vc = vlo;
    for (; vc + 8 <= vhi; vc += 8) {
        float m0 = Mp[(size_t)(vc + 0) * kN], m1 = Mp[(size_t)(vc + 1) * kN];
        float m2 = Mp[(size_t)(vc + 2) * kN], m3 = Mp[(size_t)(vc + 3) * kN];
        float m4 = Mp[(size_t)(vc + 4) * kN], m5 = Mp[(size_t)(vc + 5) * kN];
        float m6 = Mp[(size_t)(vc + 6) * kN], m7 = Mp[(size_t)(vc + 7) * kN];
#pragma unroll
        for (int i = 0; i < 22; ++i) {
            const float* hr = h + (size_t)(c0 + i) * kPc + vc;
            float4 A0 = *(const float4*)(hr);
            float4 A1 = *(const float4*)(hr + 4);
            float s = acc[i];
            s = fmaf(m0, A0.x, s); s = fmaf(m1, A0.y, s);
            s = fmaf(m2, A0.z, s); s = fmaf(m3, A0.w, s);
            s = fmaf(m4, A1.x, s); s = fmaf(m5, A1.y, s);
            s = fmaf(m6, A1.z, s); s = fmaf(m7, A1.w, s);
            acc[i] = s;
        }
    }
    for (; vc < vhi; ++vc) {
        float m = Mp[(size_t)vc * kN];
#pragma unroll
        for (int i = 0; i < 22; ++i)
            acc[i] = fmaf(m, h[(size_t)(c0 + i) * kPc + vc], acc[i]);
    }

    if (wv > 0) {
#pragma unroll
        for (int i = 0; i < 22; ++i) partial[wv - 1][i][lane] = acc[i];
    }
    __syncthreads();
    if (wv == 0 && w < kN) {
#pragma unroll
        for (int i = 0; i < 22; ++i) {
            float tot = acc[i] + partial[0][i][lane] + partial[1][i][lane];
            size_t idx = (size_t)(c0 + i) * kPc + w;
            o[idx] = gamma * tot + cAW * x[idx];
        }
    }
}

// ---------------------------------------------------------------------------
// fused hyper MLP (as R3) + zero-prologue for the adjacency sum accumulators.
// grid (164), block 768 (12 waves: s*4+m)
__global__ __launch_bounds__(768) void k_mlp(
        const float* __restrict__ xH,
        const float* __restrict__ h01, const float* __restrict__ h11,
        const float* __restrict__ h02, const float* __restrict__ h12,
        const float* __restrict__ w1, const float* __restrict__ b1,
        const float* __restrict__ w2, const float* __restrict__ b2,
        const float* __restrict__ w3, const float* __restrict__ b3,
        const float* __restrict__ e1T, const float* __restrict__ e2T,
        float* __restrict__ nv1, float* __restrict__ nv2, int hy0,
        float* __restrict__ rs, float* __restrict__ cs) {
    // zero rs/cs (consumed by k_adj next dispatch)
    {
        int zt = blockIdx.x * 768 + threadIdx.x;
        if (zt < kB * kN) rs[zt] = 0.f;
        else if (zt < 2 * kB * kN) cs[zt - kB * kN] = 0.f;
    }
    __shared__ float part[12][16][64];
    __shared__ float s2s[4][2][64];
    const int lane = threadIdx.x & 63;
    const int wv = __builtin_amdgcn_readfirstlane(threadIdx.x >> 6);
    const int p = blockIdx.x * 64 + lane;
    const int m = wv & 3, s = wv >> 2;
    const int ig = hy0 + m;
    const float* src = (s == 0) ? xH : (s == 1) ? ((m & 1) ? h11 : h01)
                                               : ((m & 1) ? h12 : h02);
    const float* wp = w1 + (size_t)ig * (kDIN * 16);
    float acc[16];
#pragma unroll
    for (int o = 0; o < 16; ++o) acc[o] = 0.f;
#pragma unroll 2
    for (int kl = 0; kl < 66; ++kl) {
        int kk = s * 66 + kl;
        float u = src[(size_t)kl * kPc + p];
        float4 wa = *(const float4*)(wp + kk * 16);
        float4 wb = *(const float4*)(wp + kk * 16 + 4);
        float4 wc = *(const float4*)(wp + kk * 16 + 8);
        float4 wd = *(const float4*)(wp + kk * 16 + 12);
        acc[0]  = fmaf(u, wa.x, acc[0]);  acc[1]  = fmaf(u, wa.y, acc[1]);
        acc[2]  = fmaf(u, wa.z, acc[2]);  acc[3]  = fmaf(u, wa.w, acc[3]);
        acc[4]  = fmaf(u, wb.x, acc[4]);  acc[5]  = fmaf(u, wb.y, acc[5]);
        acc[6]  = fmaf(u, wb.z, acc[6]);  acc[7]  = fmaf(u, wb.w, acc[7]);
        acc[8]  = fmaf(u, wc.x, acc[8]);  acc[9]  = fmaf(u, wc.y, acc[9]);
        acc[10] = fmaf(u, wc.z, acc[10]); acc[11] = fmaf(u, wc.w, acc[11]);
        acc[12] = fmaf(u, wd.x, acc[12]); acc[13] = fmaf(u, wd.y, acc[13]);
        acc[14] = fmaf(u, wd.z, acc[14]); acc[15] = fmaf(u, wd.w, acc[15]);
    }
#pragma unroll
    for (int o = 0; o < 16; ++o) part[wv][o][lane] = acc[o];
    __syncthreads();
    if (wv < 4) {
        int mm = wv, igm = hy0 + mm;
        float sv[16];
#pragma unroll
        for (int o = 0; o < 16; ++o)
            sv[o] = sigm_f(b1[igm * 16 + o] + part[mm][o][lane] + part[4 + mm][o][lane] + part[8 + mm][o][lane]);
#pragma unroll
        for (int j = 0; j < 2; ++j) {
            float t = b2[igm * 2 + j];
#pragma unroll
            for (int o = 0; o < 16; ++o) t = fmaf(sv[o], w2[igm * 32 + o * 2 + j], t);
            s2s[mm][j][lane] = sigm_f(t);
        }
    }
    __syncthreads();
    int b = p / kNP, n = p - b * kNP;
    int nc = (n < kN) ? n : (kN - 1);
    bool ok = (n < kN);
    if (wv < 2) {
        int i0 = hy0 + wv * 2;
        float sa0 = s2s[wv * 2 + 0][0][lane], sa1 = s2s[wv * 2 + 0][1][lane];
        float sb0 = s2s[wv * 2 + 1][0][lane], sb1 = s2s[wv * 2 + 1][1][lane];
        const float* eT = wv ? e2T : e1T;
        float* nv = wv ? nv2 : nv1;
#pragma unroll 4
        for (int d = 0; d < kND; ++d) {
            float f = b3[(i0 + 0) * kND + d] + b3[(i0 + 1) * kND + d]
                    + sa0 * w3[(i0 + 0) * 80 + d] + sa1 * w3[(i0 + 0) * 80 + 40 + d]
                    + sb0 * w3[(i0 + 1) * 80 + d] + sb1 * w3[(i0 + 1) * 80 + 40 + d];
            float r = tanh_f(cTA * eT[d * kN + nc] * f);
            if (ok) nv[(size_t)d * kPc + p] = r;
        }
    }
}

// ---------------------------------------------------------------------------
// fused a-GEMM + antisymmetrize + row/col sum accumulation (atomics).
// adjv[i][j] = relu(tanh(TA*(a_ij - a_ji)));  rs[b][i] += row, cs[b][j] += col
__global__ __launch_bounds__(64) void k_adj(const float* __restrict__ nv1, const float* __restrict__ nv2,
                                            float* __restrict__ adjv,
                                            float* __restrict__ rs, float* __restrict__ cs) {
    int j = blockIdx.x * 64 + threadIdx.x;
    bool jok = (j < kN);
    int jc = jok ? j : (kN - 1);
    int i0 = blockIdx.y * 16;
    int b = blockIdx.z;
    const float* p1 = nv1 + b * kNP;
    const float* p2 = nv2 + b * kNP;
    float aij[16], aji[16];
#pragma unroll
    for (int q = 0; q < 16; ++q) { aij[q] = 0.f; aji[q] = 0.f; }
#pragma unroll 2
    for (int d = 0; d < kND; ++d) {
        const float* r1 = p1 + (size_t)d * kPc;
        const float* r2 = p2 + (size_t)d * kPc;
        float x1j = r1[jc];
        float x2j = r2[jc];
        float4 v1a = *(const float4*)(r1 + i0);
        float4 v1b = *(const float4*)(r1 + i0 + 4);
        float4 v1c = *(const float4*)(r1 + i0 + 8);
        float4 v1d = *(const float4*)(r1 + i0 + 12);
        float4 v2a = *(const float4*)(r2 + i0);
        float4 v2b = *(const float4*)(r2 + i0 + 4);
        float4 v2c = *(const float4*)(r2 + i0 + 8);
        float4 v2d = *(const float4*)(r2 + i0 + 12);
        float w1v[16] = {v1a.x,v1a.y,v1a.z,v1a.w, v1b.x,v1b.y,v1b.z,v1b.w,
                         v1c.x,v1c.y,v1c.z,v1c.w, v1d.x,v1d.y,v1d.z,v1d.w};
        float w2v[16] = {v2a.x,v2a.y,v2a.z,v2a.w, v2b.x,v2b.y,v2b.z,v2b.w,
                         v2c.x,v2c.y,v2c.z,v2c.w, v2d.x,v2d.y,v2d.z,v2d.w};
#pragma unroll
        for (int q = 0; q < 16; ++q) {
            aij[q] = fmaf(w1v[q], x2j, aij[q]);
            aji[q] = fmaf(x1j, w2v[q], aji[q]);
        }
    }
    size_t base = (size_t)b * kN * kN;
    float colsum = 0.f;
#pragma unroll
    for (int q = 0; q < 16; ++q) {
        int i = i0 + q;
        float tv = tanh_f(cTA * (aij[q] - aji[q]));
        float av = fmaxf(tv, 0.f);
        bool ok = (i < kN) && jok;
        if (ok) adjv[base + (size_t)i * kN + j] = av;
        float rv = ok ? av : 0.f;
        colsum += rv;
        // wave-reduce row contribution
        float rsum = rv;
#pragma unroll
        for (int off = 32; off; off >>= 1) rsum += __shfl_down(rsum, off);
        if (threadIdx.x == 0 && i < kN) atomicAdd(&rs[b * kN + i], rsum);
    }
    if (jok) atomicAdd(&cs[b * kN + j], colsum);
}

// ---------------------------------------------------------------------------
// E0[v][w] = BW*(adjv[v][w]+I)/(1+rs[v]) + GW*adj0[v][w]
// E1[v][w] = BW*(adjv[w][v]+I)/(1+cs[v]) + GW*adj1[v][w]
__global__ __launch_bounds__(256) void k_buildE(const float* __restrict__ adjv,
                                                const float* __restrict__ adj0, const float* __restrict__ adj1,
                                                const float* __restrict__ rs, const float* __restrict__ cs,
                                                float* __restrict__ E0, float* __restrict__ E1) {
    __shared__ float tile[64][65];
    int lane = threadIdx.x & 63, wv = threadIdx.x >> 6;
    int w0 = blockIdx.x * 64, v0 = blockIdx.y * 64, b = blockIdx.z;
    const float* av = adjv + (size_t)b * kN * kN;
#pragma unroll 4
    for (int rr = 0; rr < 16; ++rr) {
        int r = wv * 16 + rr;
        int v = v0 + r, w = w0 + lane;
        tile[r][lane] = (v < kN && w < kN) ? av[(size_t)v * kN + w] : 0.f;
    }
    __syncthreads();
    size_t eb = (size_t)b * kN * kN;
#pragma unroll 2
    for (int rr = 0; rr < 16; ++rr) {
        int r = wv * 16 + rr;
        {
            int v = v0 + r, w = w0 + lane;
            if (v < kN && w < kN) {
                float iv = 1.f / (1.f + rs[b * kN + v]);
                float e = cBW * tile[r][lane] * iv + cGW * adj0[v * kN + w];
                if (v == w) e += cBW * iv;
                E0[eb + (size_t)v * kN + w] = e;
            }
        }
        {
            int v = w0 + r, w = v0 + lane;
            if (v < kN && w < kN) {
                float iv = 1.f / (1.f + cs[b * kN + v]);
                float e = cBW * tile[lane][r] * iv + cGW * adj1[v * kN + w];
                if (v == w) e += cBW * iv;
                E1[eb + (size_t)v * kN + w] = e;
            }
        }
    }
}

// ---------------------------------------------------------------------------
// z,r gates + temp=[x, r*H] into tmp. grid (164,16), block 64, barrier-free.
__global__ __launch_bounds__(64) void k_gates(
        const float* __restrict__ xH,
        const float* __restrict__ a1, const float* __restrict__ a2,
        const float* __restrict__ c1, const float* __restrict__ c2,
        const float* __restrict__ rnw, const float* __restrict__ rnb, int rb,
        float* __restrict__ z, float* __restrict__ tmp) {
    const int lane = threadIdx.x;
    const int p = blockIdx.x * 64 + lane;
    const int h0 = blockIdx.y * 4;
    const float* wz0 = rnw + (size_t)(rb + 0) * (kDIN * kHID) + h0;
    const float* wz1 = rnw + (size_t)(rb + 1) * (kDIN * kHID) + h0;
    const float* wr0 = rnw + (size_t)(rb + 2) * (kDIN * kHID) + h0;
    const float* wr1 = rnw + (size_t)(rb + 3) * (kDIN * kHID) + h0;
    float az[4] = {0.f, 0.f, 0.f, 0.f}, ar[4] = {0.f, 0.f, 0.f, 0.f};
    const float* segA[3] = {xH, a1, a2};
    const float* segB[3] = {xH, c1, c2};
#pragma unroll
    for (int seg = 0; seg < 3; ++seg) {
        const float* sA = segA[seg];
        const float* sB = segB[seg];
        const size_t wo = (size_t)seg * 66 * kHID;
#pragma unroll 2
        for (int kl = 0; kl < 66; ++kl) {
            float u0 = sA[(size_t)kl * kPc + p];
            float u1 = sB[(size_t)kl * kPc + p];
            float4 z0 = *(const float4*)(wz0 + wo + (size_t)kl * kHID);
            float4 z1 = *(const float4*)(wz1 + wo + (size_t)kl * kHID);
            float4 r0 = *(const float4*)(wr0 + wo + (size_t)kl * kHID);
            float4 r1 = *(const float4*)(wr1 + wo + (size_t)kl * kHID);
            az[0] = fmaf(u0, z0.x, az[0]); az[1] = fmaf(u0, z0.y, az[1]);
            az[2] = fmaf(u0, z0.z, az[2]); az[3] = fmaf(u0, z0.w, az[3]);
            az[0] = fmaf(u1, z1.x, az[0]); az[1] = fmaf(u1, z1.y, az[1]);
            az[2] = fmaf(u1, z1.z, az[2]); az[3] = fmaf(u1, z1.w, az[3]);
            ar[0] = fmaf(u0, r0.x, ar[0]); ar[1] = fmaf(u0, r0.y, ar[1]);
            ar[2] = fmaf(u0, r0.z, ar[2]); ar[3] = fmaf(u0, r0.w, ar[3]);
            ar[0] = fmaf(u1, r1.x, ar[0]); ar[1] = fmaf(u1, r1.y, ar[1]);
            ar[2] = fmaf(u1, r1.z, ar[2]); ar[3] = fmaf(u1, r1.w, ar[3]);
        }
    }
    int b = p / kNP, n = p - b * kNP;
    bool ok = (n < kN);
#pragma unroll
    for (int i = 0; i < 4; ++i) {
        float zz = sigm_f(az[i] + rnb[(rb + 0) * kHID + h0 + i] + rnb[(rb + 1) * kHID + h0 + i]);
        float rr = sigm_f(ar[i] + rnb[(rb + 2) * kHID + h0 + i] + rnb[(rb + 3) * kHID + h0 + i]);
        float tv = rr * xH[(size_t)(2 + h0 + i) * kPc + p];
        if (ok) {
            z[(size_t)(h0 + i) * kPc + p] = zz;
            tmp[(size_t)(2 + h0 + i) * kPc + p] = tv;
        }
    }
    if (blockIdx.y == 0 && ok) {
        tmp[p] = xH[p];
        tmp[kPc + p] = xH[kPc + p];
    }
}

// ---------------------------------------------------------------------------
// Cn + GRU update in place on xH rows 2..65, + next-step x rows.
// grid (164,16), block 64, barrier-free.
__global__ __launch_bounds__(64) void k_final(
        const float* __restrict__ tmp,
        const float* __restrict__ a1, const float* __restrict__ a2,
        const float* __restrict__ c1, const float* __restrict__ c2,
        const float* __restrict__ rnw, const float* __restrict__ rnb, int rb,
        const float* __restrict__ z, float* __restrict__ xH,
        const float* __restrict__ hist, const float* __restrict__ fut,
        int t, int nextmode) {
    const int lane = threadIdx.x;
    const int p = blockIdx.x * 64 + lane;
    const int h0 = blockIdx.y * 4;
    const float* wc0 = rnw + (size_t)(rb + 4) * (kDIN * kHID) + h0;
    const float* wc1 = rnw + (size_t)(rb + 5) * (kDIN * kHID) + h0;
    float ac[4] = {0.f, 0.f, 0.f, 0.f};
    const float* segA[3] = {tmp, a1, a2};
    const float* segB[3] = {tmp, c1, c2};
#pragma unroll
    for (int seg = 0; seg < 3; ++seg) {
        const float* sA = segA[seg];
        const float* sB = segB[seg];
        const size_t wo = (size_t)seg * 66 * kHID;
#pragma unroll 2
        for (int kl = 0; kl < 66; ++kl) {
            float u0 = sA[(size_t)kl * kPc + p];
            float u1 = sB[(size_t)kl * kPc + p];
            float4 w0 = *(const float4*)(wc0 + wo + (size_t)kl * kHID);
            float4 w1 = *(const float4*)(wc1 + wo + (size_t)kl * kHID);
            ac[0] = fmaf(u0, w0.x, ac[0]); ac[1] = fmaf(u0, w0.y, ac[1]);
            ac[2] = fmaf(u0, w0.z, ac[2]); ac[3] = fmaf(u0, w0.w, ac[3]);
            ac[0] = fmaf(u1, w1.x, ac[0]); ac[1] = fmaf(u1, w1.y, ac[1]);
            ac[2] = fmaf(u1, w1.z, ac[2]); ac[3] = fmaf(u1, w1.w, ac[3]);
        }
    }
    int b = p / kNP, n = p - b * kNP;
    bool ok = (n < kN);
#pragma unroll
    for (int i = 0; i < 4; ++i) {
        float cn = tanh_f(ac[i] + rnb[(rb + 4) * kHID + h0 + i] + rnb[(rb + 5) * kHID + h0 + i]);
        float zz = z[(size_t)(h0 + i) * kPc + p];
        size_t hidx = (size_t)(2 + h0 + i) * kPc + p;
        float hv = xH[hidx];
        if (ok) xH[hidx] = zz * hv + (1.f - zz) * cn;
    }
    if (blockIdx.y == 0 && ok && nextmode != 2) {
        float r0, r1;
        if (nextmode == 0) {
            r0 = hist[((b * kL + (t + 1)) * kN + n) * 2 + 0];
            r1 = hist[((b * kL + (t + 1)) * kN + n) * 2 + 1];
        } else {
            r0 = 0.f;
            r1 = fut[((b * kL + 0) * kN + n) * 2 + 1];
        }
        xH[p] = r0;
        xH[kPc + p] = r1;
    }
}

// decoder readout: out = H @ fc_w + fc_b ; also write next dec x rows
__global__ __launch_bounds__(64) void k_out(const float* __restrict__ xH,
                                            const float* __restrict__ fw, const float* __restrict__ fb,
                                            float* __restrict__ out, const float* __restrict__ fut,
                                            float* __restrict__ xHw, int t) {
    int p = blockIdx.x * 64 + threadIdx.x;
    int b = p / kNP, n = p - b * kNP;
    if (n >= kN) return;
    float acc = fb[0];
#pragma unroll
    for (int h = 0; h < kHID; ++h) acc = fmaf(xH[(size_t)(2 + h) * kPc + p], fw[h], acc);
    out[(b * 12 + t) * kN + n] = acc;
    if (t + 1 < 12) {
        xHw[p] = acc;
        xHw[kPc + p] = fut[((b * kL + (t + 1)) * kN + n) * 2 + 1];
    }
}

// ---------------------------------------------------------------------------
extern "C" void kernel_launch(void* const* d_in, const int* in_sizes, int n_in,
                              void* d_out, int out_size, void* d_ws, size_t ws_size,
                              hipStream_t stream) {
    const float* hist = (const float*)d_in[0];
    const float* fut  = (const float*)d_in[1];
    const float* adj0 = (const float*)d_in[2];
    const float* adj1 = (const float*)d_in[3];
    const float* emb1 = (const float*)d_in[4];
    const float* emb2 = (const float*)d_in[5];
    const float* hw1  = (const float*)d_in[6];
    const float* hb1  = (const float*)d_in[7];
    const float* hw2  = (const float*)d_in[8];
    const float* hb2  = (const float*)d_in[9];
    const float* hw3  = (const float*)d_in[10];
    const float* hb3  = (const float*)d_in[11];
    const float* rnw  = (const float*)d_in[12];
    const float* rnb  = (const float*)d_in[13];
    const float* fcw  = (const float*)d_in[14];
    const float* fcb  = (const float*)d_in[15];
    float* out = (float*)d_out;
    float* ws  = (float*)d_ws;

    const size_t SEG = (size_t)66 * kPc;
    size_t off = 0;
    float* xH   = ws + off; off += SEG;
    float* hy0h1= ws + off; off += SEG;
    float* hy1h1= ws + off; off += SEG;
    float* hy0h2= ws + off; off += SEG;
    float* hy1h2= ws + off; off += SEG;
    float* z0h1 = ws + off; off += SEG;
    float* z1h1 = ws + off; off += SEG;
    float* z0h2 = ws + off; off += SEG;
    float* z1h2 = ws + off; off += SEG;
    float* tmp  = ws + off; off += SEG;
    float* c0h1 = ws + off; off += SEG;
    float* c1h1 = ws + off; off += SEG;
    float* c0h2 = ws + off; off += SEG;
    float* c1h2 = ws + off; off += SEG;
    float* nv1  = ws + off; off += (size_t)kND * kPc;
    float* nv2  = ws + off; off += (size_t)kND * kPc;
    float* zbuf = ws + off; off += (size_t)64 * kPc;
    float* e1T  = ws + off; off += kND * kN;
    float* e2T  = ws + off; off += kND * kN;
    float* rsb  = ws + off; off += kB * kN;
    float* csb  = ws + off; off += kB * kN;
    float* adjv = ws + off; off += (size_t)kB * kN * kN;
    float* E0   = ws + off; off += (size_t)kB * kN * kN;
    float* E1   = ws + off; off += (size_t)kB * kN * kN;

    const int NN2 = kN * kN;

    {
        int tot = 66 * kPc + 2 * kND * kN;
        k_init<<<dim3((tot + 255) / 256), dim3(256), 0, stream>>>(hist, emb1, emb2, xH, e1T, e2T);
    }

    for (int step = 0; step < 24; ++step) {
        int dec = step >= 12;
        int t = dec ? step - 12 : step;
        int hy0 = dec ? 4 : 0;
        int rb = dec ? 6 : 0;
        int nextmode = dec ? 2 : (step == 11 ? 1 : 0);

        // hyper diffusion (static adjacencies, shared across batch)
        k_hop<<<dim3(6, 3, 64), dim3(192), 0, stream>>>(
            adj0, adj1, 0, xH, xH, xH, hy0h1, hy1h1, cGW);
        k_hop<<<dim3(6, 3, 64), dim3(192), 0, stream>>>(
            adj0, adj1, 0, hy0h1, hy1h1, xH, hy0h2, hy1h2, cGW);

        k_mlp<<<dim3(kPc / 64), dim3(768), 0, stream>>>(
            xH, hy0h1, hy1h1, hy0h2, hy1h2, hw1, hb1, hw2, hb2, hw3, hb3,
            e1T, e2T, nv1, nv2, hy0, rsb, csb);

        k_adj<<<dim3(6, 21, kB), dim3(64), 0, stream>>>(nv1, nv2, adjv, rsb, csb);
        k_buildE<<<dim3(6, 6, kB), dim3(256), 0, stream>>>(adjv, adj0, adj1, rsb, csb, E0, E1);

        // z/r diffusion
        k_hop<<<dim3(6, 3, 64), dim3(192), 0, stream>>>(
            E0, E1, NN2, xH, xH, xH, z0h1, z1h1, 1.f);
        k_hop<<<dim3(6, 3, 64), dim3(192), 0, stream>>>(
            E0, E1, NN2, z0h1, z1h1, xH, z0h2, z1h2, 1.f);

        k_gates<<<dim3(kPc / 64, 16), dim3(64), 0, stream>>>(
            xH, z0h1, z0h2, z1h1, z1h2, rnw, rnb, rb, zbuf, tmp);

        // candidate diffusion
        k_hop<<<dim3(6, 3, 64), dim3(192), 0, stream>>>(
            E0, E1, NN2, tmp, tmp, tmp, c0h1, c1h1, 1.f);
        k_hop<<<dim3(6, 3, 64), dim3(192), 0, stream>>>(
            E0, E1, NN2, c0h1, c1h1, tmp, c0h2, c1h2, 1.f);

        k_final<<<dim3(kPc / 64, 16), dim3(64), 0, stream>>>(
            tmp, c0h1, c0h2, c1h1, c1h2, rnw, rnb, rb, zbuf, xH, hist, fut, t, nextmode);

        if (dec)
            k_out<<<dim3(kPc / 64), dim3(64), 0, stream>>>(xH, fcw, fcb, out, fut, xH, t);
    }
    (void)in_sizes; (void)n_in; (void)out_size; (void)ws_size;
}